// Round 3
// baseline (323.382 us; speedup 1.0000x reference)
//
#include <hip/hip_runtime.h>

#define TI 3
#define NCH (1152 / TI)            // 384 i-chunks
#define SLICES 32
#define SCELLS (128 * 10 * 16)     // 20480
#define PADX 28                    // 24 floats of x per row + 4 pad (7 float4 slots)

// DPP add helper: v += lane-permuted v. CTRL: 0xB1 = quad_perm [1,0,3,2] (xor1),
// 0x4E = quad_perm [2,3,0,1] (xor2), 0x128 = row_ror:8 (xor8 within 16-lane row).
template<int CTRL>
__device__ __forceinline__ float dpp_add(float v) {
    int o = __builtin_amdgcn_update_dpp(0, __float_as_int(v), CTRL, 0xf, 0xf, true);
    return v + __int_as_float(o);
}
// xor4 lane exchange via ds_swizzle BitMode: (4<<10) | 0x1F
__device__ __forceinline__ float swz_xor4(float v) {
    return __int_as_float(__builtin_amdgcn_ds_swizzle(__float_as_int(v), 0x101F));
}

// ---------------------------------------------------------------------------
// Pass kernel. 256 threads = 4 waves, block covers (i-chunk TI=3) x (64 b's).
// Thread map: dl = lane bits {0,1,3} (d-low octet, d = dl + 8h);
//             jh = bit 2 (j half); b-group = bits {4..7}: bL = ((tid>>4)&15)*4
// Per thread: 4 b x 5 j x 2 d = 40 u-values per il.
// W in LDS is slot-swizzled: slot' = slot ^ ((slot>>3)&1)  (slot = 16B unit)
// Grid (384, 2) = 768 blocks = exactly 3/CU resident -> 12 waves/CU.
// ---------------------------------------------------------------------------
template<int ITER>
__global__ __launch_bounds__(256, 4)
void caps_pass(const float* __restrict__ x, const float* __restrict__ W,
               const float* __restrict__ vin, float* __restrict__ s_part)
{
    __shared__ float sW[TI * 1280];      // 15.4 KB, swizzled 16B slots
    __shared__ float sX[64 * PADX];      // 7.2 KB

    const int ic  = blockIdx.x;          // [0,384)
    const int bq  = blockIdx.y;          // [0,2)
    const int i0  = ic * TI;
    const int b0  = bq * 64;
    const int tid = threadIdx.x;

    // ---- stage W chunk with slot swizzle ----
    {
        const float4* Wg  = reinterpret_cast<const float4*>(W + (size_t)i0 * 1280);
        float4*       sWf = reinterpret_cast<float4*>(sW);
        for (int t = tid; t < TI * 320; t += 256) {
            int il = t / 320, S = t % 320;
            int Sp = S ^ ((S >> 3) & 1);
            sWf[il * 320 + Sp] = Wg[t];
        }
    }
    // ---- stage x chunk: 64 rows x 24 contiguous floats, padded stride 28 ----
    {
        float4* sXf = reinterpret_cast<float4*>(sX);
        for (int t = tid; t < 64 * 6; t += 256) {
            int r = t / 6, c = t % 6;
            sXf[r * 7 + c] = *reinterpret_cast<const float4*>(
                x + (size_t)(b0 + r) * 9216 + i0 * 8 + c * 4);
        }
    }
    __syncthreads();

    const int dl = (tid & 3) | ((tid >> 1) & 4);   // lane bits 0,1,3
    const int jh = (tid >> 2) & 1;
    const int bL = ((tid >> 4) & 15) * 4;          // [0,64) step 4

    // v registers (constant over il) — only for ITER >= 1
    float vr[4][5][2];
    if (ITER >= 1) {
#pragma unroll
        for (int bb = 0; bb < 4; ++bb)
#pragma unroll
            for (int jj = 0; jj < 5; ++jj)
#pragma unroll
                for (int h = 0; h < 2; ++h)
                    vr[bb][jj][h] = vin[(size_t)(b0 + bL + bb) * 160 +
                                        (jh * 5 + jj) * 16 + dl + 8 * h];
    }

    float s_acc[4][5][2];
#pragma unroll
    for (int bb = 0; bb < 4; ++bb)
#pragma unroll
        for (int jj = 0; jj < 5; ++jj)
#pragma unroll
            for (int h = 0; h < 2; ++h) s_acc[bb][jj][h] = 0.f;

#pragma unroll 1
    for (int il = 0; il < TI; ++il) {
        // x for my 4 b's
        float xr[4][8];
#pragma unroll
        for (int bb = 0; bb < 4; ++bb) {
            const float4* px = reinterpret_cast<const float4*>(&sX[(bL + bb) * PADX + il * 8]);
            float4 a = px[0], b = px[1];
            xr[bb][0] = a.x; xr[bb][1] = a.y; xr[bb][2] = a.z; xr[bb][3] = a.w;
            xr[bb][4] = b.x; xr[bb][5] = b.y; xr[bb][6] = b.z; xr[bb][7] = b.w;
        }
        // u_hat for my (4b x 5j x 2d)
        float u[4][5][2];
#pragma unroll
        for (int jj = 0; jj < 5; ++jj) {
#pragma unroll
            for (int h = 0; h < 2; ++h) {
                const int j  = jh * 5 + jj;
                const int d  = dl + 8 * h;
                const int S0 = j * 32 + d * 2;          // even 16B slot
                const int sw = (S0 >> 3) & 1;           // d bit2 -> bank-bit inject
                const float4 w0 = *reinterpret_cast<const float4*>(
                    &sW[il * 1280 + (S0 ^ sw) * 4]);
                const float4 w1 = *reinterpret_cast<const float4*>(
                    &sW[il * 1280 + ((S0 + 1) ^ sw) * 4]);
#pragma unroll
                for (int bb = 0; bb < 4; ++bb) {
                    float acc = w0.x * xr[bb][0];
                    acc = fmaf(w0.y, xr[bb][1], acc);
                    acc = fmaf(w0.z, xr[bb][2], acc);
                    acc = fmaf(w0.w, xr[bb][3], acc);
                    acc = fmaf(w1.x, xr[bb][4], acc);
                    acc = fmaf(w1.y, xr[bb][5], acc);
                    acc = fmaf(w1.z, xr[bb][6], acc);
                    acc = fmaf(w1.w, xr[bb][7], acc);
                    u[bb][jj][h] = acc;
                }
            }
        }

        float c[4][5];
        if (ITER == 0) {
#pragma unroll
            for (int bb = 0; bb < 4; ++bb)
#pragma unroll
                for (int jj = 0; jj < 5; ++jj) c[bb][jj] = 0.1f;
        } else {
            // logit = sum_d u*v : in-thread d-pair, then DPP over lane bits 0,1,3
            float lp[4][5];
#pragma unroll
            for (int bb = 0; bb < 4; ++bb)
#pragma unroll
                for (int jj = 0; jj < 5; ++jj) {
                    float t = fmaf(u[bb][jj][1], vr[bb][jj][1],
                                   u[bb][jj][0] * vr[bb][jj][0]);
                    t = dpp_add<0xB1>(t);    // xor1
                    t = dpp_add<0x4E>(t);    // xor2
                    t = dpp_add<0x128>(t);   // xor8 (row_ror:8)
                    lp[bb][jj] = t;
                }
            // softmax over 10 j: 5 local + partner half via xor4 swizzle
#pragma unroll
            for (int bb = 0; bb < 4; ++bb) {
                float mx = fmaxf(fmaxf(fmaxf(lp[bb][0], lp[bb][1]),
                                       fmaxf(lp[bb][2], lp[bb][3])), lp[bb][4]);
                mx = fmaxf(mx, swz_xor4(mx));
                float e0 = __expf(lp[bb][0] - mx);
                float e1 = __expf(lp[bb][1] - mx);
                float e2 = __expf(lp[bb][2] - mx);
                float e3 = __expf(lp[bb][3] - mx);
                float e4 = __expf(lp[bb][4] - mx);
                float sm = e0 + e1 + e2 + e3 + e4;
                sm += swz_xor4(sm);
                float inv = 1.0f / sm;
                c[bb][0] = e0 * inv; c[bb][1] = e1 * inv; c[bb][2] = e2 * inv;
                c[bb][3] = e3 * inv; c[bb][4] = e4 * inv;
            }
        }
        // s += c * u
#pragma unroll
        for (int bb = 0; bb < 4; ++bb)
#pragma unroll
            for (int jj = 0; jj < 5; ++jj)
#pragma unroll
                for (int h = 0; h < 2; ++h)
                    s_acc[bb][jj][h] = fmaf(c[bb][jj], u[bb][jj][h], s_acc[bb][jj][h]);
    }

    // epilogue: atomic accumulate into contention slice (12 writers/cell/slice)
    float* sp = s_part + (size_t)(ic & (SLICES - 1)) * SCELLS;
#pragma unroll
    for (int bb = 0; bb < 4; ++bb)
#pragma unroll
        for (int jj = 0; jj < 5; ++jj)
#pragma unroll
            for (int h = 0; h < 2; ++h)
                atomicAdd(&sp[(b0 + bL + bb) * 160 + (jh * 5 + jj) * 16 + dl + 8 * h],
                          s_acc[bb][jj][h]);
}

// ---------------------------------------------------------------------------
// Squash kernel: sum 32 slices + bias, squash along d (16 lanes/row shuffle),
// write v; re-zero slices for the next pass.
// MODE 0: v_out = squash(s)            (writes vA = v0)
// MODE 1: v_out = v_prev + squash(s)   (writes vB = v0+v1)
// MODE 2: v_out = squash(s)            (final -> d_out, no re-zero)
// ---------------------------------------------------------------------------
template<int MODE>
__global__ __launch_bounds__(256)
void caps_squash(float* __restrict__ s_part, const float* __restrict__ bias,
                 const float* __restrict__ v_prev, float* __restrict__ v_out)
{
    const int gid = blockIdx.x * 256 + threadIdx.x;   // [0, 20480)
    const int row = gid >> 4;                         // b*10 + j
    const int j   = row % 10;

    float sd = bias[j * 16 + (gid & 15)];
#pragma unroll
    for (int g = 0; g < SLICES; ++g) sd += s_part[g * SCELLS + gid];
    if (MODE != 2) {
#pragma unroll
        for (int g = 0; g < SLICES; ++g) s_part[g * SCELLS + gid] = 0.f;
    }

    float sq = sd * sd;
    sq += __shfl_xor(sq, 1, 64);
    sq += __shfl_xor(sq, 2, 64);
    sq += __shfl_xor(sq, 4, 64);
    sq += __shfl_xor(sq, 8, 64);

    float scale = sq / ((1.0f + sq) * sqrtf(sq + 1e-7f));
    float v = sd * scale;

    if (MODE == 1) v = v_prev[gid] + v;
    v_out[gid] = v;
}

extern "C" void kernel_launch(void* const* d_in, const int* in_sizes, int n_in,
                              void* d_out, int out_size, void* d_ws, size_t ws_size,
                              hipStream_t stream)
{
    const float* x    = (const float*)d_in[0];
    const float* W    = (const float*)d_in[1];
    const float* bias = (const float*)d_in[2];
    float* out = (float*)d_out;

    float* s_part = (float*)d_ws;                 // 32 * 20480 floats = 2.6 MB
    float* vA     = s_part + SLICES * SCELLS;     // 20480 floats (v0)
    float* vB     = vA + SCELLS;                  // 20480 floats (v0+v1)

    hipMemsetAsync(s_part, 0, (size_t)SLICES * SCELLS * sizeof(float), stream);

    dim3 pgrid(NCH, 2);
    caps_pass<0><<<pgrid, 256, 0, stream>>>(x, W, nullptr, s_part);
    caps_squash<0><<<SCELLS / 256, 256, 0, stream>>>(s_part, bias, nullptr, vA);
    caps_pass<1><<<pgrid, 256, 0, stream>>>(x, W, vA, s_part);
    caps_squash<1><<<SCELLS / 256, 256, 0, stream>>>(s_part, bias, vA, vB);
    caps_pass<2><<<pgrid, 256, 0, stream>>>(x, W, vB, s_part);
    caps_squash<2><<<SCELLS / 256, 256, 0, stream>>>(s_part, bias, nullptr, out);
}

// Round 4
// 211.556 us; speedup vs baseline: 1.5286x; 1.5286x over previous
//
#include <hip/hip_runtime.h>

#define TI 4
#define NCH (1152 / TI)            // 288 i-chunks
#define SLICES 32
#define SCELLS (128 * 10 * 16)     // 20480
#define PADX 36                    // 32 floats of x per row + 4 pad (9 float4 slots)

// DPP add helper: v += lane-permuted v. CTRL: 0xB1 = quad_perm [1,0,3,2] (xor1),
// 0x4E = quad_perm [2,3,0,1] (xor2), 0x128 = row_ror:8 (xor8 within 16-lane row).
template<int CTRL>
__device__ __forceinline__ float dpp_add(float v) {
    int o = __builtin_amdgcn_update_dpp(0, __float_as_int(v), CTRL, 0xf, 0xf, true);
    return v + __int_as_float(o);
}
// xor4 lane exchange via ds_swizzle BitMode: (4<<10) | 0x1F
__device__ __forceinline__ float swz_xor4(float v) {
    return __int_as_float(__builtin_amdgcn_ds_swizzle(__float_as_int(v), 0x101F));
}

// ---------------------------------------------------------------------------
// Pass kernel. 256 threads = 4 waves; block covers (i-chunk TI=4) x (32 b's).
// Thread map: dl = lane bits {0,1,3} (d-low octet, d = dl + 8h);
//             jh = bit 2 (j half); b-group = bits {4..7}: bL = ((tid>>4)&15)*2
// Per thread: 2 b x 5 j x 2 d = 20 u-values per il  (~85-110 live VGPRs).
// W in LDS slot-swizzled: slot' = slot ^ ((slot>>3)&1)  (slot = 16B unit).
// Grid (288, 4) = 1152 blocks x 4 waves = 4608 waves ~ 18 waves/CU.
// ---------------------------------------------------------------------------
template<int ITER>
__global__ __launch_bounds__(256, 2)
void caps_pass(const float* __restrict__ x, const float* __restrict__ W,
               const float* __restrict__ vin, float* __restrict__ s_part)
{
    __shared__ float sW[TI * 1280];      // 20.5 KB, swizzled 16B slots
    __shared__ float sX[32 * PADX];      // 4.6 KB

    const int ic  = blockIdx.x;          // [0,288)
    const int bq  = blockIdx.y;          // [0,4)
    const int i0  = ic * TI;
    const int b0  = bq * 32;
    const int tid = threadIdx.x;

    // ---- stage W chunk with slot swizzle ----
    {
        const float4* Wg  = reinterpret_cast<const float4*>(W + (size_t)i0 * 1280);
        float4*       sWf = reinterpret_cast<float4*>(sW);
        for (int t = tid; t < TI * 320; t += 256) {
            int il = t / 320, S = t % 320;
            int Sp = S ^ ((S >> 3) & 1);
            sWf[il * 320 + Sp] = Wg[t];
        }
    }
    // ---- stage x chunk: 32 rows x 32 contiguous floats, padded stride 36 ----
    {
        float4* sXf = reinterpret_cast<float4*>(sX);
        for (int t = tid; t < 32 * 8; t += 256) {
            int r = t / 8, c = t % 8;
            sXf[r * 9 + c] = *reinterpret_cast<const float4*>(
                x + (size_t)(b0 + r) * 9216 + i0 * 8 + c * 4);
        }
    }
    __syncthreads();

    const int dl = (tid & 3) | ((tid >> 1) & 4);   // lane bits 0,1,3
    const int jh = (tid >> 2) & 1;
    const int bL = ((tid >> 4) & 15) * 2;          // [0,32) step 2

    // v registers (constant over il) — only for ITER >= 1
    float vr[2][5][2];
    if (ITER >= 1) {
#pragma unroll
        for (int bb = 0; bb < 2; ++bb)
#pragma unroll
            for (int jj = 0; jj < 5; ++jj)
#pragma unroll
                for (int h = 0; h < 2; ++h)
                    vr[bb][jj][h] = vin[(size_t)(b0 + bL + bb) * 160 +
                                        (jh * 5 + jj) * 16 + dl + 8 * h];
    }

    float s_acc[2][5][2];
#pragma unroll
    for (int bb = 0; bb < 2; ++bb)
#pragma unroll
        for (int jj = 0; jj < 5; ++jj)
#pragma unroll
            for (int h = 0; h < 2; ++h) s_acc[bb][jj][h] = 0.f;

#pragma unroll 1
    for (int il = 0; il < TI; ++il) {
        // x for my 2 b's
        float xr[2][8];
#pragma unroll
        for (int bb = 0; bb < 2; ++bb) {
            const float4* px = reinterpret_cast<const float4*>(&sX[(bL + bb) * PADX + il * 8]);
            float4 a = px[0], b = px[1];
            xr[bb][0] = a.x; xr[bb][1] = a.y; xr[bb][2] = a.z; xr[bb][3] = a.w;
            xr[bb][4] = b.x; xr[bb][5] = b.y; xr[bb][6] = b.z; xr[bb][7] = b.w;
        }
        // u_hat for my (2b x 5j x 2d)
        float u[2][5][2];
#pragma unroll
        for (int jj = 0; jj < 5; ++jj) {
#pragma unroll
            for (int h = 0; h < 2; ++h) {
                const int j  = jh * 5 + jj;
                const int d  = dl + 8 * h;
                const int S0 = j * 32 + d * 2;          // even 16B slot
                const int sw = (S0 >> 3) & 1;           // d bit2 -> bank-bit inject
                const float4 w0 = *reinterpret_cast<const float4*>(
                    &sW[il * 1280 + (S0 ^ sw) * 4]);
                const float4 w1 = *reinterpret_cast<const float4*>(
                    &sW[il * 1280 + ((S0 + 1) ^ sw) * 4]);
#pragma unroll
                for (int bb = 0; bb < 2; ++bb) {
                    float acc = w0.x * xr[bb][0];
                    acc = fmaf(w0.y, xr[bb][1], acc);
                    acc = fmaf(w0.z, xr[bb][2], acc);
                    acc = fmaf(w0.w, xr[bb][3], acc);
                    acc = fmaf(w1.x, xr[bb][4], acc);
                    acc = fmaf(w1.y, xr[bb][5], acc);
                    acc = fmaf(w1.z, xr[bb][6], acc);
                    acc = fmaf(w1.w, xr[bb][7], acc);
                    u[bb][jj][h] = acc;
                }
            }
        }

        float c[2][5];
        if (ITER == 0) {
#pragma unroll
            for (int bb = 0; bb < 2; ++bb)
#pragma unroll
                for (int jj = 0; jj < 5; ++jj) c[bb][jj] = 0.1f;
        } else {
            // logit = sum_d u*v : in-thread d-pair, then DPP over lane bits 0,1,3
            float lp[2][5];
#pragma unroll
            for (int bb = 0; bb < 2; ++bb)
#pragma unroll
                for (int jj = 0; jj < 5; ++jj) {
                    float t = fmaf(u[bb][jj][1], vr[bb][jj][1],
                                   u[bb][jj][0] * vr[bb][jj][0]);
                    t = dpp_add<0xB1>(t);    // xor1
                    t = dpp_add<0x4E>(t);    // xor2
                    t = dpp_add<0x128>(t);   // xor8 (row_ror:8)
                    lp[bb][jj] = t;
                }
            // softmax over 10 j: 5 local + partner half via xor4 swizzle
#pragma unroll
            for (int bb = 0; bb < 2; ++bb) {
                float mx = fmaxf(fmaxf(fmaxf(lp[bb][0], lp[bb][1]),
                                       fmaxf(lp[bb][2], lp[bb][3])), lp[bb][4]);
                mx = fmaxf(mx, swz_xor4(mx));
                float e0 = __expf(lp[bb][0] - mx);
                float e1 = __expf(lp[bb][1] - mx);
                float e2 = __expf(lp[bb][2] - mx);
                float e3 = __expf(lp[bb][3] - mx);
                float e4 = __expf(lp[bb][4] - mx);
                float sm = e0 + e1 + e2 + e3 + e4;
                sm += swz_xor4(sm);
                float inv = 1.0f / sm;
                c[bb][0] = e0 * inv; c[bb][1] = e1 * inv; c[bb][2] = e2 * inv;
                c[bb][3] = e3 * inv; c[bb][4] = e4 * inv;
            }
        }
        // s += c * u
#pragma unroll
        for (int bb = 0; bb < 2; ++bb)
#pragma unroll
            for (int jj = 0; jj < 5; ++jj)
#pragma unroll
                for (int h = 0; h < 2; ++h)
                    s_acc[bb][jj][h] = fmaf(c[bb][jj], u[bb][jj][h], s_acc[bb][jj][h]);
    }

    // epilogue: atomic accumulate into contention slice (9 writer-blocks/cell/slice)
    float* sp = s_part + (size_t)(ic & (SLICES - 1)) * SCELLS;
#pragma unroll
    for (int bb = 0; bb < 2; ++bb)
#pragma unroll
        for (int jj = 0; jj < 5; ++jj)
#pragma unroll
            for (int h = 0; h < 2; ++h)
                atomicAdd(&sp[(b0 + bL + bb) * 160 + (jh * 5 + jj) * 16 + dl + 8 * h],
                          s_acc[bb][jj][h]);
}

// ---------------------------------------------------------------------------
// Squash kernel: sum 32 slices + bias, squash along d (16 lanes/row shuffle),
// write v; re-zero slices for the next pass.
// MODE 0: v_out = squash(s)            (writes vA = v0)
// MODE 1: v_out = v_prev + squash(s)   (writes vB = v0+v1)
// MODE 2: v_out = squash(s)            (final -> d_out, no re-zero)
// ---------------------------------------------------------------------------
template<int MODE>
__global__ __launch_bounds__(256)
void caps_squash(float* __restrict__ s_part, const float* __restrict__ bias,
                 const float* __restrict__ v_prev, float* __restrict__ v_out)
{
    const int gid = blockIdx.x * 256 + threadIdx.x;   // [0, 20480)
    const int row = gid >> 4;                         // b*10 + j
    const int j   = row % 10;

    float sd = bias[j * 16 + (gid & 15)];
#pragma unroll
    for (int g = 0; g < SLICES; ++g) sd += s_part[g * SCELLS + gid];
    if (MODE != 2) {
#pragma unroll
        for (int g = 0; g < SLICES; ++g) s_part[g * SCELLS + gid] = 0.f;
    }

    float sq = sd * sd;
    sq += __shfl_xor(sq, 1, 64);
    sq += __shfl_xor(sq, 2, 64);
    sq += __shfl_xor(sq, 4, 64);
    sq += __shfl_xor(sq, 8, 64);

    float scale = sq / ((1.0f + sq) * sqrtf(sq + 1e-7f));
    float v = sd * scale;

    if (MODE == 1) v = v_prev[gid] + v;
    v_out[gid] = v;
}

extern "C" void kernel_launch(void* const* d_in, const int* in_sizes, int n_in,
                              void* d_out, int out_size, void* d_ws, size_t ws_size,
                              hipStream_t stream)
{
    const float* x    = (const float*)d_in[0];
    const float* W    = (const float*)d_in[1];
    const float* bias = (const float*)d_in[2];
    float* out = (float*)d_out;

    float* s_part = (float*)d_ws;                 // 32 * 20480 floats = 2.6 MB
    float* vA     = s_part + SLICES * SCELLS;     // 20480 floats (v0)
    float* vB     = vA + SCELLS;                  // 20480 floats (v0+v1)

    hipMemsetAsync(s_part, 0, (size_t)SLICES * SCELLS * sizeof(float), stream);

    dim3 pgrid(NCH, 4);
    caps_pass<0><<<pgrid, 256, 0, stream>>>(x, W, nullptr, s_part);
    caps_squash<0><<<SCELLS / 256, 256, 0, stream>>>(s_part, bias, nullptr, vA);
    caps_pass<1><<<pgrid, 256, 0, stream>>>(x, W, vA, s_part);
    caps_squash<1><<<SCELLS / 256, 256, 0, stream>>>(s_part, bias, vA, vB);
    caps_pass<2><<<pgrid, 256, 0, stream>>>(x, W, vB, s_part);
    caps_squash<2><<<SCELLS / 256, 256, 0, stream>>>(s_part, bias, nullptr, out);
}

// Round 5
// 137.496 us; speedup vs baseline: 2.3519x; 1.5386x over previous
//
#include <hip/hip_runtime.h>

#define TI 4
#define NCH (1152 / TI)            // 288 i-chunks = 288 partials
#define SCELLS (128 * 10 * 16)     // 20480 cells (b,j,d)
#define PADX 36                    // 32 floats of x per row + 4 pad (9 float4 slots)

// DPP add helper: v += lane-permuted v. CTRL: 0xB1 = quad_perm [1,0,3,2] (xor1),
// 0x4E = quad_perm [2,3,0,1] (xor2), 0x128 = row_ror:8 (xor8 within 16-lane row).
template<int CTRL>
__device__ __forceinline__ float dpp_add(float v) {
    int o = __builtin_amdgcn_update_dpp(0, __float_as_int(v), CTRL, 0xf, 0xf, true);
    return v + __int_as_float(o);
}
// xor4 lane exchange via ds_swizzle BitMode: (4<<10) | 0x1F
__device__ __forceinline__ float swz_xor4(float v) {
    return __int_as_float(__builtin_amdgcn_ds_swizzle(__float_as_int(v), 0x101F));
}

// ---------------------------------------------------------------------------
// Pass kernel (same body as R4 — VGPR=60, no spills). 256 threads = 4 waves;
// block covers (i-chunk TI=4) x (32 b's). Grid (288,4) -> 18 waves/CU.
// EPILOGUE CHANGE: plain stores into p[ic][cell] (disjoint per block, full
// coverage -> no pre-zero needed), replacing the rate-limited global atomics.
// ---------------------------------------------------------------------------
template<int ITER>
__global__ __launch_bounds__(256, 2)
void caps_pass(const float* __restrict__ x, const float* __restrict__ W,
               const float* __restrict__ vin, float* __restrict__ p)
{
    __shared__ float sW[TI * 1280];      // 20.5 KB, swizzled 16B slots
    __shared__ float sX[32 * PADX];      // 4.6 KB

    const int ic  = blockIdx.x;          // [0,288)
    const int bq  = blockIdx.y;          // [0,4)
    const int i0  = ic * TI;
    const int b0  = bq * 32;
    const int tid = threadIdx.x;

    // ---- stage W chunk with slot swizzle ----
    {
        const float4* Wg  = reinterpret_cast<const float4*>(W + (size_t)i0 * 1280);
        float4*       sWf = reinterpret_cast<float4*>(sW);
        for (int t = tid; t < TI * 320; t += 256) {
            int il = t / 320, S = t % 320;
            int Sp = S ^ ((S >> 3) & 1);
            sWf[il * 320 + Sp] = Wg[t];
        }
    }
    // ---- stage x chunk: 32 rows x 32 contiguous floats, padded stride 36 ----
    {
        float4* sXf = reinterpret_cast<float4*>(sX);
        for (int t = tid; t < 32 * 8; t += 256) {
            int r = t / 8, c = t % 8;
            sXf[r * 9 + c] = *reinterpret_cast<const float4*>(
                x + (size_t)(b0 + r) * 9216 + i0 * 8 + c * 4);
        }
    }
    __syncthreads();

    const int dl = (tid & 3) | ((tid >> 1) & 4);   // lane bits 0,1,3
    const int jh = (tid >> 2) & 1;
    const int bL = ((tid >> 4) & 15) * 2;          // [0,32) step 2

    // v registers (constant over il) — only for ITER >= 1
    float vr[2][5][2];
    if (ITER >= 1) {
#pragma unroll
        for (int bb = 0; bb < 2; ++bb)
#pragma unroll
            for (int jj = 0; jj < 5; ++jj)
#pragma unroll
                for (int h = 0; h < 2; ++h)
                    vr[bb][jj][h] = vin[(size_t)(b0 + bL + bb) * 160 +
                                        (jh * 5 + jj) * 16 + dl + 8 * h];
    }

    float s_acc[2][5][2];
#pragma unroll
    for (int bb = 0; bb < 2; ++bb)
#pragma unroll
        for (int jj = 0; jj < 5; ++jj)
#pragma unroll
            for (int h = 0; h < 2; ++h) s_acc[bb][jj][h] = 0.f;

#pragma unroll 1
    for (int il = 0; il < TI; ++il) {
        // x for my 2 b's
        float xr[2][8];
#pragma unroll
        for (int bb = 0; bb < 2; ++bb) {
            const float4* px = reinterpret_cast<const float4*>(&sX[(bL + bb) * PADX + il * 8]);
            float4 a = px[0], b = px[1];
            xr[bb][0] = a.x; xr[bb][1] = a.y; xr[bb][2] = a.z; xr[bb][3] = a.w;
            xr[bb][4] = b.x; xr[bb][5] = b.y; xr[bb][6] = b.z; xr[bb][7] = b.w;
        }
        // u_hat for my (2b x 5j x 2d)
        float u[2][5][2];
#pragma unroll
        for (int jj = 0; jj < 5; ++jj) {
#pragma unroll
            for (int h = 0; h < 2; ++h) {
                const int j  = jh * 5 + jj;
                const int d  = dl + 8 * h;
                const int S0 = j * 32 + d * 2;          // even 16B slot
                const int sw = (S0 >> 3) & 1;           // d bit2 -> bank-bit inject
                const float4 w0 = *reinterpret_cast<const float4*>(
                    &sW[il * 1280 + (S0 ^ sw) * 4]);
                const float4 w1 = *reinterpret_cast<const float4*>(
                    &sW[il * 1280 + ((S0 + 1) ^ sw) * 4]);
#pragma unroll
                for (int bb = 0; bb < 2; ++bb) {
                    float acc = w0.x * xr[bb][0];
                    acc = fmaf(w0.y, xr[bb][1], acc);
                    acc = fmaf(w0.z, xr[bb][2], acc);
                    acc = fmaf(w0.w, xr[bb][3], acc);
                    acc = fmaf(w1.x, xr[bb][4], acc);
                    acc = fmaf(w1.y, xr[bb][5], acc);
                    acc = fmaf(w1.z, xr[bb][6], acc);
                    acc = fmaf(w1.w, xr[bb][7], acc);
                    u[bb][jj][h] = acc;
                }
            }
        }

        float c[2][5];
        if (ITER == 0) {
#pragma unroll
            for (int bb = 0; bb < 2; ++bb)
#pragma unroll
                for (int jj = 0; jj < 5; ++jj) c[bb][jj] = 0.1f;
        } else {
            // logit = sum_d u*v : in-thread d-pair, then DPP over lane bits 0,1,3
            float lp[2][5];
#pragma unroll
            for (int bb = 0; bb < 2; ++bb)
#pragma unroll
                for (int jj = 0; jj < 5; ++jj) {
                    float t = fmaf(u[bb][jj][1], vr[bb][jj][1],
                                   u[bb][jj][0] * vr[bb][jj][0]);
                    t = dpp_add<0xB1>(t);    // xor1
                    t = dpp_add<0x4E>(t);    // xor2
                    t = dpp_add<0x128>(t);   // xor8 (row_ror:8)
                    lp[bb][jj] = t;
                }
            // softmax over 10 j: 5 local + partner half via xor4 swizzle
#pragma unroll
            for (int bb = 0; bb < 2; ++bb) {
                float mx = fmaxf(fmaxf(fmaxf(lp[bb][0], lp[bb][1]),
                                       fmaxf(lp[bb][2], lp[bb][3])), lp[bb][4]);
                mx = fmaxf(mx, swz_xor4(mx));
                float e0 = __expf(lp[bb][0] - mx);
                float e1 = __expf(lp[bb][1] - mx);
                float e2 = __expf(lp[bb][2] - mx);
                float e3 = __expf(lp[bb][3] - mx);
                float e4 = __expf(lp[bb][4] - mx);
                float sm = e0 + e1 + e2 + e3 + e4;
                sm += swz_xor4(sm);
                float inv = 1.0f / sm;
                c[bb][0] = e0 * inv; c[bb][1] = e1 * inv; c[bb][2] = e2 * inv;
                c[bb][3] = e3 * inv; c[bb][4] = e4 * inv;
            }
        }
        // s += c * u
#pragma unroll
        for (int bb = 0; bb < 2; ++bb)
#pragma unroll
            for (int jj = 0; jj < 5; ++jj)
#pragma unroll
                for (int h = 0; h < 2; ++h)
                    s_acc[bb][jj][h] = fmaf(c[bb][jj], u[bb][jj][h], s_acc[bb][jj][h]);
    }

    // epilogue: plain stores (no atomics). Block (ic,bq) owns disjoint cells.
    float* pp = p + (size_t)ic * SCELLS;
#pragma unroll
    for (int bb = 0; bb < 2; ++bb)
#pragma unroll
        for (int jj = 0; jj < 5; ++jj)
#pragma unroll
            for (int h = 0; h < 2; ++h)
                pp[(b0 + bL + bb) * 160 + (jh * 5 + jj) * 16 + dl + 8 * h] =
                    s_acc[bb][jj][h];
}

// ---------------------------------------------------------------------------
// Squash kernel: reduce 288 partials + bias, squash along d, write v.
// 320 blocks x 256 threads; block owns 64 cells; wave w reduces ic in
// [w*72, w*72+72) with coalesced 256B reads; LDS-combine; wave 0 finishes.
// MODE 0: v_out = squash(s)            (vA = v0)
// MODE 1: v_out = v_prev + squash(s)   (vB = v0+v1)
// MODE 2: v_out = squash(s)            (final -> d_out)
// ---------------------------------------------------------------------------
template<int MODE>
__global__ __launch_bounds__(256)
void caps_squash(const float* __restrict__ p, const float* __restrict__ bias,
                 const float* __restrict__ v_prev, float* __restrict__ v_out)
{
    __shared__ float part[4][64];
    const int tid  = threadIdx.x;
    const int w    = tid >> 6;
    const int lane = tid & 63;
    const int c    = blockIdx.x * 64 + lane;

    float acc = 0.f;
    const float* pw = p + (size_t)(w * (NCH / 4)) * SCELLS + c;
#pragma unroll 8
    for (int t = 0; t < NCH / 4; ++t) acc += pw[(size_t)t * SCELLS];
    part[w][lane] = acc;
    __syncthreads();

    if (tid < 64) {
        const int cc = blockIdx.x * 64 + tid;
        float tot = part[0][tid] + part[1][tid] + part[2][tid] + part[3][tid]
                  + bias[cc % 160];   // cc%160 = j*16+d

        float sq = tot * tot;
        sq += __shfl_xor(sq, 1, 64);
        sq += __shfl_xor(sq, 2, 64);
        sq += __shfl_xor(sq, 4, 64);
        sq += __shfl_xor(sq, 8, 64);

        float scale = sq / ((1.0f + sq) * sqrtf(sq + 1e-7f));
        float v = tot * scale;

        if (MODE == 1) v += v_prev[cc];
        v_out[cc] = v;
    }
}

extern "C" void kernel_launch(void* const* d_in, const int* in_sizes, int n_in,
                              void* d_out, int out_size, void* d_ws, size_t ws_size,
                              hipStream_t stream)
{
    const float* x    = (const float*)d_in[0];
    const float* W    = (const float*)d_in[1];
    const float* bias = (const float*)d_in[2];
    float* out = (float*)d_out;

    float* p  = (float*)d_ws;                     // 288 * 20480 floats = 23.6 MB
    float* vA = p + (size_t)NCH * SCELLS;         // 20480 floats (v0)
    float* vB = vA + SCELLS;                      // 20480 floats (v0+v1)

    dim3 pgrid(NCH, 4);
    dim3 sgrid(SCELLS / 64);
    caps_pass<0><<<pgrid, 256, 0, stream>>>(x, W, nullptr, p);
    caps_squash<0><<<sgrid, 256, 0, stream>>>(p, bias, nullptr, vA);
    caps_pass<1><<<pgrid, 256, 0, stream>>>(x, W, vA, p);
    caps_squash<1><<<sgrid, 256, 0, stream>>>(p, bias, vA, vB);
    caps_pass<2><<<pgrid, 256, 0, stream>>>(x, W, vB, p);
    caps_squash<2><<<sgrid, 256, 0, stream>>>(p, bias, nullptr, out);
}